// Round 8
// baseline (206.289 us; speedup 1.0000x reference)
//
#include <hip/hip_runtime.h>

typedef unsigned short u16;
typedef __attribute__((ext_vector_type(8))) short short8;
typedef __attribute__((ext_vector_type(4))) short short4v;
typedef __attribute__((ext_vector_type(2))) int int2v;
typedef __attribute__((ext_vector_type(4))) float f32x4;

#define DIM   768
#define HEADS 12
#define HD    64
#define BATCH 8
#define SEQ   1024
#define MTOK  (BATCH*SEQ)   /* 8192 */
#define NQKV  (3*DIM)       /* 2304 */
#define KPAD  72            /* attn LDS row stride: 36 dwords breaks 32-bank alias */
#define EPAD  66            /* gemm epilogue stage stride */
#define PSZ   ((size_t)BATCH*HEADS*SEQ*HD)   /* one of q/k/v */
#define SCQ   0.1803368801f /* hd^-0.5 * log2(e), folded into stored q */

__device__ __forceinline__ u16 f2bf(float f) {
  unsigned x = __float_as_uint(f);
  x += 0x7fffu + ((x >> 16) & 1u);      // RNE
  return (u16)(x >> 16);
}

__device__ __forceinline__ void gload16(const u16* g, u16* l) {
  __builtin_amdgcn_global_load_lds(
      (const __attribute__((address_space(1))) unsigned int*)g,
      (__attribute__((address_space(3))) unsigned int*)l, 16, 0, 0);
}

// ---------------- fused conversions: x->bf16, Wqkv^T, Wproj^T ----------------
#define XBLK 6144            /* MTOK*DIM/4/256 */
#define QTBLK 1728           /* (NQKV/32)*(DIM/32) */
__global__ void cvt_all_k(const float* __restrict__ x,
                          const float* __restrict__ Wqkv,
                          const float* __restrict__ Wproj,
                          u16* __restrict__ xb, u16* __restrict__ wqkvt,
                          u16* __restrict__ wprojt) {
  __shared__ u16 tile[32][33];
  const int blk = blockIdx.x;
  if (blk < XBLK) {
    const int i = blk * 256 + threadIdx.x;
    float4 f = ((const float4*)x)[i];
    short4v o;
    o.x = (short)f2bf(f.x); o.y = (short)f2bf(f.y);
    o.z = (short)f2bf(f.z); o.w = (short)f2bf(f.w);
    ((short4v*)xb)[i] = o;
    return;
  }
  const float* in; u16* out; int K, N, n0, k0;
  if (blk < XBLK + QTBLK) {
    const int t = blk - XBLK;
    in = Wqkv; out = wqkvt; K = DIM; N = NQKV;
    n0 = (t % (NQKV / 32)) * 32; k0 = (t / (NQKV / 32)) * 32;
  } else {
    const int t = blk - XBLK - QTBLK;
    in = Wproj; out = wprojt; K = DIM; N = DIM;
    n0 = (t % (DIM / 32)) * 32; k0 = (t / (DIM / 32)) * 32;
  }
  const int tx = threadIdx.x & 31, ty = threadIdx.x >> 5;
  #pragma unroll
  for (int i = 0; i < 32; i += 8)
    tile[ty + i][tx] = f2bf(in[(size_t)(k0 + ty + i) * N + n0 + tx]);
  __syncthreads();
  #pragma unroll
  for (int i = 0; i < 32; i += 8)
    out[(size_t)(n0 + ty + i) * K + k0 + tx] = tile[tx][ty + i];
}

// ---------------- GEMM1: qkv = x * Wqkv^T + b, 128x128 tile, BK=64 ----------------
// 1152 blocks (4.5/CU) for TLP; qkv layout [part][bh][t][d]; LDS-transpose epilogue
__global__ __launch_bounds__(256)
void gemm_qkv(const u16* __restrict__ A, const u16* __restrict__ Bt,
              const float* __restrict__ bias, u16* __restrict__ qkv) {
  __shared__ __align__(16) u16 smem[4 * 128 * 32];   // 32 KB
  u16* lA0 = smem;
  u16* lA1 = smem + 128 * 32;
  u16* lB0 = smem + 2 * 128 * 32;
  u16* lB1 = smem + 3 * 128 * 32;
  const int w = threadIdx.x >> 6, lane = threadIdx.x & 63;
  const int l15 = lane & 15, quad = lane >> 4;
  const int m0 = blockIdx.y * 128, n0 = blockIdx.x * 128;
  const int wm = (w >> 1) * 64, wn = (w & 1) * 64;

  f32x4 acc[4][4] = {};

  const int ar = threadIdx.x >> 2, ak = (threadIdx.x & 3) * 8;
  const u16* ga = A  + (size_t)(m0 + ar) * DIM + ak;
  const u16* gb = Bt + (size_t)(n0 + ar) * DIM + ak;
  const int lo = threadIdx.x * 8;

  for (int k0 = 0; k0 < DIM; k0 += 64) {
    #pragma unroll
    for (int t = 0; t < 2; ++t) {
      gload16(ga + (size_t)t * 64 * DIM + k0,      lA0 + lo + t * 2048);
      gload16(ga + (size_t)t * 64 * DIM + k0 + 32, lA1 + lo + t * 2048);
      gload16(gb + (size_t)t * 64 * DIM + k0,      lB0 + lo + t * 2048);
      gload16(gb + (size_t)t * 64 * DIM + k0 + 32, lB1 + lo + t * 2048);
    }
    __syncthreads();

    #pragma unroll
    for (int kh = 0; kh < 2; ++kh) {
      const u16* lAh = kh ? lA1 : lA0;
      const u16* lBh = kh ? lB1 : lB0;
      short8 af[4], bfr[4];
      #pragma unroll
      for (int mt = 0; mt < 4; ++mt)
        af[mt] = *(const short8*)&lAh[(wm + mt * 16 + l15) * 32 + quad * 8];
      #pragma unroll
      for (int nt = 0; nt < 4; ++nt)
        bfr[nt] = *(const short8*)&lBh[(wn + nt * 16 + l15) * 32 + quad * 8];
      #pragma unroll
      for (int mt = 0; mt < 4; ++mt)
        #pragma unroll
        for (int nt = 0; nt < 4; ++nt)
          acc[mt][nt] = __builtin_amdgcn_mfma_f32_16x16x32_bf16(af[mt], bfr[nt], acc[mt][nt], 0, 0, 0);
    }
    __syncthreads();
  }

  const int bb = m0 >> 10;
  const int tb0 = (m0 & 1023) + wm;
  const int nh = n0 + wn;
  const int part = nh / DIM, idx = nh - part * DIM;
  const int h = idx >> 6;
  u16* dstbase = qkv + part * PSZ + ((size_t)(bb * HEADS + h) * SEQ + tb0) * HD;
  const float qsc = (part == 0) ? SCQ : 1.0f;   // fold softmax scale into q

  float bnl[4];
  #pragma unroll
  for (int nt = 0; nt < 4; ++nt) bnl[nt] = bias[nh + nt * 16 + l15];

  const int erow = lane >> 3, ec8 = (lane & 7) * 8;
  #pragma unroll
  for (int mt = 0; mt < 4; ++mt) {
    u16* ep = smem + w * (16 * EPAD) + (mt & 1) * (4 * 16 * EPAD);
    #pragma unroll
    for (int nt = 0; nt < 4; ++nt)
      #pragma unroll
      for (int r = 0; r < 4; ++r)
        ep[(quad * 4 + r) * EPAD + nt * 16 + l15] = f2bf((acc[mt][nt][r] + bnl[nt]) * qsc);
    #pragma unroll
    for (int j = 0; j < 2; ++j) {
      const int trow = j * 8 + erow;
      short8 vrow = *(const short8*)&ep[trow * EPAD + ec8];
      *(short8*)(dstbase + (size_t)(mt * 16 + trow) * HD + ec8) = vrow;  // 1KB/instr
    }
  }
}

// ---------------- v [bh][t][d] -> vt [bh][d][t]  (bf16 transpose) ----------------
__global__ void vt_k(const u16* __restrict__ v, u16* __restrict__ vt) {
  __shared__ u16 tl[64][72];
  const int bh = blockIdx.y, t0 = blockIdx.x * 64;
  #pragma unroll
  for (int i = 0; i < 2; ++i) {
    const int c = threadIdx.x + i * 256;
    const int tr = c >> 3, dc8 = c & 7;
    const int cc = dc8 ^ (tr >> 3);
    *(short8*)&tl[tr][cc * 8] = *(const short8*)(v + ((size_t)bh * SEQ + t0 + tr) * HD + dc8 * 8);
  }
  __syncthreads();
  #pragma unroll
  for (int i = 0; i < 2; ++i) {
    const int c = threadIdx.x + i * 256;
    const int dr = c >> 3, tc = (c & 7) * 8;
    short8 outv;
    #pragma unroll
    for (int j = 0; j < 8; ++j) {
      const int t = tc + j;
      const int cc = (dr >> 3) ^ (t >> 3);
      outv[j] = (short)tl[t][cc * 8 + (dr & 7)];
    }
    *(short8*)(vt + ((size_t)bh * HD + dr) * SEQ + t0 + tc) = outv;
  }
}

// ---------------- GEMM2: out = y * Wproj^T + b (fp32 out, 128x128, BK=64) ----------------
__global__ __launch_bounds__(256)
void gemm_proj(const u16* __restrict__ A, const u16* __restrict__ Bt,
               const float* __restrict__ bias, float* __restrict__ outF) {
  __shared__ __align__(16) u16 smem[4 * 128 * 32];   // 32 KB
  u16* lA0 = smem;
  u16* lA1 = smem + 128 * 32;
  u16* lB0 = smem + 2 * 128 * 32;
  u16* lB1 = smem + 3 * 128 * 32;
  const int w = threadIdx.x >> 6, lane = threadIdx.x & 63;
  const int l15 = lane & 15, quad = lane >> 4;
  const int m0 = blockIdx.y * 128, n0 = blockIdx.x * 128;
  const int wm = (w >> 1) * 64, wn = (w & 1) * 64;

  f32x4 acc[4][4] = {};

  const int ar = threadIdx.x >> 2, ak = (threadIdx.x & 3) * 8;
  const u16* ga = A  + (size_t)(m0 + ar) * DIM + ak;
  const u16* gb = Bt + (size_t)(n0 + ar) * DIM + ak;
  const int lo = threadIdx.x * 8;

  for (int k0 = 0; k0 < DIM; k0 += 64) {
    #pragma unroll
    for (int t = 0; t < 2; ++t) {
      gload16(ga + (size_t)t * 64 * DIM + k0,      lA0 + lo + t * 2048);
      gload16(ga + (size_t)t * 64 * DIM + k0 + 32, lA1 + lo + t * 2048);
      gload16(gb + (size_t)t * 64 * DIM + k0,      lB0 + lo + t * 2048);
      gload16(gb + (size_t)t * 64 * DIM + k0 + 32, lB1 + lo + t * 2048);
    }
    __syncthreads();

    #pragma unroll
    for (int kh = 0; kh < 2; ++kh) {
      const u16* lAh = kh ? lA1 : lA0;
      const u16* lBh = kh ? lB1 : lB0;
      short8 af[4], bfr[4];
      #pragma unroll
      for (int mt = 0; mt < 4; ++mt)
        af[mt] = *(const short8*)&lAh[(wm + mt * 16 + l15) * 32 + quad * 8];
      #pragma unroll
      for (int nt = 0; nt < 4; ++nt)
        bfr[nt] = *(const short8*)&lBh[(wn + nt * 16 + l15) * 32 + quad * 8];
      #pragma unroll
      for (int mt = 0; mt < 4; ++mt)
        #pragma unroll
        for (int nt = 0; nt < 4; ++nt)
          acc[mt][nt] = __builtin_amdgcn_mfma_f32_16x16x32_bf16(af[mt], bfr[nt], acc[mt][nt], 0, 0, 0);
    }
    __syncthreads();
  }

  #pragma unroll
  for (int nt = 0; nt < 4; ++nt) {
    const int n = n0 + wn + nt * 16 + l15;
    const float bn = bias[n];
    #pragma unroll
    for (int mt = 0; mt < 4; ++mt)
      #pragma unroll
      for (int r = 0; r < 4; ++r) {
        const int m = m0 + wm + mt * 16 + quad * 4 + r;
        outF[(size_t)m * DIM + n] = acc[mt][nt][r] + bn;
      }
  }
}

// ---------------- flash attention: 128-row Q tiles, S^T, max-free ----------------
// grid (8, 96). block 256 = 4 waves x 32 q-rows. K/V staged via REGISTER PREFETCH:
// loads for chunk kc+1 issue before compute of kc -> vmcnt wait hides behind compute.
__global__ __launch_bounds__(256)
void attn_k(const u16* __restrict__ qb, const u16* __restrict__ kb,
            const u16* __restrict__ vtb, u16* __restrict__ yb) {
  const int qt = blockIdx.x, bh = blockIdx.y;
  const int w = threadIdx.x >> 6, lane = threadIdx.x & 63;
  const int l15 = lane & 15, quad = lane >> 4;

  __shared__ __align__(16) u16 lK[64 * KPAD];      // [key][d]
  __shared__ __align__(16) u16 lV[64 * KPAD];      // [d][key]
  __shared__ __align__(16) u16 lP[4][32 * KPAD];   // per-wave [qrow 0..31][key]

  const u16* qb0 = qb + ((size_t)bh * SEQ + qt * 128 + w * 32 + l15) * HD;
  short8 aq[2][2];
  #pragma unroll
  for (int qg = 0; qg < 2; ++qg) {
    aq[qg][0] = *(const short8*)(qb0 + (size_t)qg * 16 * HD + quad * 8);
    aq[qg][1] = *(const short8*)(qb0 + (size_t)qg * 16 * HD + 32 + quad * 8);
  }

  f32x4 o[2][4] = {};
  float rs[2] = {0.f, 0.f};

  const u16* kcbase = kb + (size_t)bh * SEQ * HD;
  const u16* vbase  = vtb + (size_t)bh * HD * SEQ;
  u16* lPw = &lP[w][0];

  // staging geometry (loop-invariant)
  const int cid0 = threadIdx.x, cid1 = threadIdx.x + 256;
  const int sofs0 = (cid0 >> 3) * KPAD + (cid0 & 7) * 8;
  const int sofs1 = (cid1 >> 3) * KPAD + (cid1 & 7) * 8;
  const u16* vg0 = vbase + (size_t)(cid0 >> 3) * SEQ + (cid0 & 7) * 8;
  const u16* vg1 = vbase + (size_t)(cid1 >> 3) * SEQ + (cid1 & 7) * 8;

  // prologue: prefetch chunk 0 into registers
  short8 pk0 = *(const short8*)(kcbase + cid0 * 8);
  short8 pk1 = *(const short8*)(kcbase + cid1 * 8);
  short8 pv0 = *(const short8*)vg0;
  short8 pv1 = *(const short8*)vg1;

  for (int kc = 0; kc < 16; ++kc) {
    // commit prefetched chunk to LDS (vmcnt wait covered by prior compute)
    *(short8*)&lK[sofs0] = pk0;
    *(short8*)&lK[sofs1] = pk1;
    *(short8*)&lV[sofs0] = pv0;
    *(short8*)&lV[sofs1] = pv1;
    __syncthreads();

    // issue next chunk's loads now; they stay in flight across the compute
    const int kn = (kc < 15) ? kc + 1 : 15;
    pk0 = *(const short8*)(kcbase + kn * 64 * HD + cid0 * 8);
    pk1 = *(const short8*)(kcbase + kn * 64 * HD + cid1 * 8);
    pv0 = *(const short8*)(vg0 + kn * 64);
    pv1 = *(const short8*)(vg1 + kn * 64);

    short8 ak0[4], ak1[4], bv0[4], bv1[4];
    #pragma unroll
    for (int nt = 0; nt < 4; ++nt) {
      ak0[nt] = *(const short8*)&lK[(nt * 16 + l15) * KPAD + quad * 8];
      ak1[nt] = *(const short8*)&lK[(nt * 16 + l15) * KPAD + 32 + quad * 8];
      bv0[nt] = *(const short8*)&lV[(nt * 16 + l15) * KPAD + quad * 8];
      bv1[nt] = *(const short8*)&lV[(nt * 16 + l15) * KPAD + 32 + quad * 8];
    }

    #pragma unroll
    for (int qg = 0; qg < 2; ++qg) {
      f32x4 st[4] = {};
      #pragma unroll
      for (int nt = 0; nt < 4; ++nt) {
        st[nt] = __builtin_amdgcn_mfma_f32_16x16x32_bf16(ak0[nt], aq[qg][0], st[nt], 0, 0, 0);
        st[nt] = __builtin_amdgcn_mfma_f32_16x16x32_bf16(ak1[nt], aq[qg][1], st[nt], 0, 0, 0);
      }

      #pragma unroll
      for (int nt = 0; nt < 4; ++nt) {
        float p0 = __builtin_amdgcn_exp2f(st[nt][0]);
        float p1 = __builtin_amdgcn_exp2f(st[nt][1]);
        float p2 = __builtin_amdgcn_exp2f(st[nt][2]);
        float p3 = __builtin_amdgcn_exp2f(st[nt][3]);
        float t0 = __uint_as_float(__float_as_uint(p0) & 0xffff0000u);
        float t1 = __uint_as_float(__float_as_uint(p1) & 0xffff0000u);
        float t2 = __uint_as_float(__float_as_uint(p2) & 0xffff0000u);
        float t3 = __uint_as_float(__float_as_uint(p3) & 0xffff0000u);
        rs[qg] += (t0 + t1) + (t2 + t3);
        int2v pk;
        pk.x = (int)__builtin_amdgcn_perm(__float_as_uint(p1), __float_as_uint(p0), 0x07060302u);
        pk.y = (int)__builtin_amdgcn_perm(__float_as_uint(p3), __float_as_uint(p2), 0x07060302u);
        *(int2v*)&lPw[(qg * 16 + l15) * KPAD + nt * 16 + quad * 4] = pk;
      }
      const short8 ap0 = *(const short8*)&lPw[(qg * 16 + l15) * KPAD + quad * 8];
      const short8 ap1 = *(const short8*)&lPw[(qg * 16 + l15) * KPAD + 32 + quad * 8];
      #pragma unroll
      for (int nt = 0; nt < 4; ++nt) {
        o[qg][nt] = __builtin_amdgcn_mfma_f32_16x16x32_bf16(ap0, bv0[nt], o[qg][nt], 0, 0, 0);
        o[qg][nt] = __builtin_amdgcn_mfma_f32_16x16x32_bf16(ap1, bv1[nt], o[qg][nt], 0, 0, 0);
      }
    }
    __syncthreads();
  }

  const int b = bh / HEADS, h = bh % HEADS;
  #pragma unroll
  for (int qg = 0; qg < 2; ++qg) {
    rs[qg] += __shfl_xor(rs[qg], 16);
    rs[qg] += __shfl_xor(rs[qg], 32);
    #pragma unroll
    for (int r = 0; r < 4; ++r) {
      const float inv = 1.0f / __shfl(rs[qg], quad * 4 + r, 16);
      #pragma unroll
      for (int nt = 0; nt < 4; ++nt)
        lPw[(qg * 16 + quad * 4 + r) * KPAD + nt * 16 + l15] = f2bf(o[qg][nt][r] * inv);
    }
  }

  u16* dst = yb + ((size_t)b * SEQ + qt * 128 + w * 32) * DIM + h * HD;
  const int erow = lane >> 3, ec8 = (lane & 7) * 8;
  #pragma unroll
  for (int j = 0; j < 4; ++j) {
    const int trow = j * 8 + erow;
    short8 vrow = *(const short8*)&lPw[trow * KPAD + ec8];
    *(short8*)(dst + (size_t)trow * DIM + ec8) = vrow;
  }
}

// ---------------- launcher ----------------
extern "C" void kernel_launch(void* const* d_in, const int* in_sizes, int n_in,
                              void* d_out, int out_size, void* d_ws, size_t ws_size,
                              hipStream_t stream) {
  const float* x     = (const float*)d_in[0];
  const float* Wqkv  = (const float*)d_in[1];
  const float* bqkv  = (const float*)d_in[2];
  const float* Wproj = (const float*)d_in[3];
  const float* bproj = (const float*)d_in[4];
  float* out = (float*)d_out;

  u16* xb     = (u16*)d_ws;                       // 8192*768 (reused as vt later)
  u16* wqkvt  = xb + (size_t)MTOK * DIM;
  u16* wprojt = wqkvt + (size_t)NQKV * DIM;
  u16* qkv_b  = wprojt + (size_t)DIM * DIM;       // [part][bh][t][d]
  u16* y_b    = qkv_b + 3 * PSZ;
  u16* vt_b   = xb;

  cvt_all_k<<<XBLK + QTBLK + (DIM / 32) * (DIM / 32), 256, 0, stream>>>(
      x, Wqkv, Wproj, xb, wqkvt, wprojt);

  gemm_qkv<<<dim3(NQKV / 128, MTOK / 128), 256, 0, stream>>>(xb, wqkvt, bqkv, qkv_b);

  vt_k<<<dim3(SEQ / 64, BATCH * HEADS), 256, 0, stream>>>(qkv_b + 2 * PSZ, vt_b);

  attn_k<<<dim3(SEQ / 128, BATCH * HEADS), 256, 0, stream>>>(
      qkv_b, qkv_b + PSZ, vt_b, y_b);

  gemm_proj<<<dim3(DIM / 128, MTOK / 128), 256, 0, stream>>>(y_b, wprojt, bproj, out);
}

// Round 9
// 203.659 us; speedup vs baseline: 1.0129x; 1.0129x over previous
//
#include <hip/hip_runtime.h>

typedef unsigned short u16;
typedef __attribute__((ext_vector_type(8))) short short8;
typedef __attribute__((ext_vector_type(4))) short short4v;
typedef __attribute__((ext_vector_type(2))) int int2v;
typedef __attribute__((ext_vector_type(4))) float f32x4;

#define DIM   768
#define HEADS 12
#define HD    64
#define BATCH 8
#define SEQ   1024
#define MTOK  (BATCH*SEQ)   /* 8192 */
#define NQKV  (3*DIM)       /* 2304 */
#define KPAD  72            /* attn LDS row stride: 36 dwords breaks 32-bank alias */
#define EPAD  66            /* gemm epilogue stage stride */
#define PSZ   ((size_t)BATCH*HEADS*SEQ*HD)   /* one of q/k/v */
#define SCQ   0.1803368801f /* hd^-0.5 * log2(e), folded into stored q */

__device__ __forceinline__ u16 f2bf(float f) {
  unsigned x = __float_as_uint(f);
  x += 0x7fffu + ((x >> 16) & 1u);      // RNE
  return (u16)(x >> 16);
}

__device__ __forceinline__ void gload16(const u16* g, u16* l) {
  __builtin_amdgcn_global_load_lds(
      (const __attribute__((address_space(1))) unsigned int*)g,
      (__attribute__((address_space(3))) unsigned int*)l, 16, 0, 0);
}

// ---------------- fused conversions: x->bf16, Wqkv^T, Wproj^T ----------------
#define XBLK 6144            /* MTOK*DIM/4/256 */
#define QTBLK 1728           /* (NQKV/32)*(DIM/32) */
__global__ void cvt_all_k(const float* __restrict__ x,
                          const float* __restrict__ Wqkv,
                          const float* __restrict__ Wproj,
                          u16* __restrict__ xb, u16* __restrict__ wqkvt,
                          u16* __restrict__ wprojt) {
  __shared__ u16 tile[32][33];
  const int blk = blockIdx.x;
  if (blk < XBLK) {
    const int i = blk * 256 + threadIdx.x;
    float4 f = ((const float4*)x)[i];
    short4v o;
    o.x = (short)f2bf(f.x); o.y = (short)f2bf(f.y);
    o.z = (short)f2bf(f.z); o.w = (short)f2bf(f.w);
    ((short4v*)xb)[i] = o;
    return;
  }
  const float* in; u16* out; int K, N, n0, k0;
  if (blk < XBLK + QTBLK) {
    const int t = blk - XBLK;
    in = Wqkv; out = wqkvt; K = DIM; N = NQKV;
    n0 = (t % (NQKV / 32)) * 32; k0 = (t / (NQKV / 32)) * 32;
  } else {
    const int t = blk - XBLK - QTBLK;
    in = Wproj; out = wprojt; K = DIM; N = DIM;
    n0 = (t % (DIM / 32)) * 32; k0 = (t / (DIM / 32)) * 32;
  }
  const int tx = threadIdx.x & 31, ty = threadIdx.x >> 5;
  #pragma unroll
  for (int i = 0; i < 32; i += 8)
    tile[ty + i][tx] = f2bf(in[(size_t)(k0 + ty + i) * N + n0 + tx]);
  __syncthreads();
  #pragma unroll
  for (int i = 0; i < 32; i += 8)
    out[(size_t)(n0 + ty + i) * K + k0 + tx] = tile[tx][ty + i];
}

// ---------------- GEMM1: qkv = x * Wqkv^T + b, 128x128 tile, BK=64 ----------------
// q/k: [part][bh][t][d] via LDS-transpose epilogue (full-line stores).
// v:   written DIRECTLY as vt [bh][d][t] via per-lane short4 stores
//      (4 consecutive t per lane; mt-consecutive instrs fill each 64B line).
__global__ __launch_bounds__(256)
void gemm_qkv(const u16* __restrict__ A, const u16* __restrict__ Bt,
              const float* __restrict__ bias, u16* __restrict__ qkv) {
  __shared__ __align__(16) u16 smem[4 * 128 * 32];   // 32 KB
  u16* lA0 = smem;
  u16* lA1 = smem + 128 * 32;
  u16* lB0 = smem + 2 * 128 * 32;
  u16* lB1 = smem + 3 * 128 * 32;
  const int w = threadIdx.x >> 6, lane = threadIdx.x & 63;
  const int l15 = lane & 15, quad = lane >> 4;
  const int m0 = blockIdx.y * 128, n0 = blockIdx.x * 128;
  const int wm = (w >> 1) * 64, wn = (w & 1) * 64;

  f32x4 acc[4][4] = {};

  const int ar = threadIdx.x >> 2, ak = (threadIdx.x & 3) * 8;
  const u16* ga = A  + (size_t)(m0 + ar) * DIM + ak;
  const u16* gb = Bt + (size_t)(n0 + ar) * DIM + ak;
  const int lo = threadIdx.x * 8;

  for (int k0 = 0; k0 < DIM; k0 += 64) {
    #pragma unroll
    for (int t = 0; t < 2; ++t) {
      gload16(ga + (size_t)t * 64 * DIM + k0,      lA0 + lo + t * 2048);
      gload16(ga + (size_t)t * 64 * DIM + k0 + 32, lA1 + lo + t * 2048);
      gload16(gb + (size_t)t * 64 * DIM + k0,      lB0 + lo + t * 2048);
      gload16(gb + (size_t)t * 64 * DIM + k0 + 32, lB1 + lo + t * 2048);
    }
    __syncthreads();

    #pragma unroll
    for (int kh = 0; kh < 2; ++kh) {
      const u16* lAh = kh ? lA1 : lA0;
      const u16* lBh = kh ? lB1 : lB0;
      short8 af[4], bfr[4];
      #pragma unroll
      for (int mt = 0; mt < 4; ++mt)
        af[mt] = *(const short8*)&lAh[(wm + mt * 16 + l15) * 32 + quad * 8];
      #pragma unroll
      for (int nt = 0; nt < 4; ++nt)
        bfr[nt] = *(const short8*)&lBh[(wn + nt * 16 + l15) * 32 + quad * 8];
      #pragma unroll
      for (int mt = 0; mt < 4; ++mt)
        #pragma unroll
        for (int nt = 0; nt < 4; ++nt)
          acc[mt][nt] = __builtin_amdgcn_mfma_f32_16x16x32_bf16(af[mt], bfr[nt], acc[mt][nt], 0, 0, 0);
    }
    __syncthreads();
  }

  const int bb = m0 >> 10;
  const int tb0 = (m0 & 1023) + wm;
  const int nh = n0 + wn;
  const int part = nh / DIM, idx = nh - part * DIM;
  const int h = idx >> 6;

  float bnl[4];
  #pragma unroll
  for (int nt = 0; nt < 4; ++nt) bnl[nt] = bias[nh + nt * 16 + l15];

  if (part < 2) {
    // q/k: LDS-transpose -> full 128B-row stores into [part][bh][t][d]
    u16* dstbase = qkv + part * PSZ + ((size_t)(bb * HEADS + h) * SEQ + tb0) * HD;
    const float qsc = (part == 0) ? SCQ : 1.0f;
    const int erow = lane >> 3, ec8 = (lane & 7) * 8;
    #pragma unroll
    for (int mt = 0; mt < 4; ++mt) {
      u16* ep = smem + w * (16 * EPAD) + (mt & 1) * (4 * 16 * EPAD);
      #pragma unroll
      for (int nt = 0; nt < 4; ++nt)
        #pragma unroll
        for (int r = 0; r < 4; ++r)
          ep[(quad * 4 + r) * EPAD + nt * 16 + l15] = f2bf((acc[mt][nt][r] + bnl[nt]) * qsc);
      #pragma unroll
      for (int j = 0; j < 2; ++j) {
        const int trow = j * 8 + erow;
        short8 vrow = *(const short8*)&ep[trow * EPAD + ec8];
        *(short8*)(dstbase + (size_t)(mt * 16 + trow) * HD + ec8) = vrow;  // 1KB/instr
      }
    }
  } else {
    // v: direct short4 stores to vt [bh][d][t] (lane holds 4 consecutive t)
    u16* vrow0 = qkv + 2 * PSZ + (size_t)(bb * HEADS + h) * HD * SEQ;
    #pragma unroll
    for (int nt = 0; nt < 4; ++nt) {
      const int d = nt * 16 + l15;
      u16* trow = vrow0 + (size_t)d * SEQ + tb0 + quad * 4;
      #pragma unroll
      for (int mt = 0; mt < 4; ++mt) {   // mt-consecutive: fills 64B lines pairwise
        short4v pv;
        pv.x = (short)f2bf(acc[mt][nt][0] + bnl[nt]);
        pv.y = (short)f2bf(acc[mt][nt][1] + bnl[nt]);
        pv.z = (short)f2bf(acc[mt][nt][2] + bnl[nt]);
        pv.w = (short)f2bf(acc[mt][nt][3] + bnl[nt]);
        *(short4v*)(trow + mt * 16) = pv;
      }
    }
  }
}

// ---------------- GEMM2: out = y * Wproj^T + b (fp32 out, 128x64, BK=64) ----------------
// 768 blocks (3/CU) vs previous 384 (1.5/CU): kills the half-empty tail.
__global__ __launch_bounds__(256)
void gemm_proj(const u16* __restrict__ A, const u16* __restrict__ Bt,
               const float* __restrict__ bias, float* __restrict__ outF) {
  __shared__ __align__(16) u16 smem[2 * 128 * 32 + 2 * 64 * 32];   // 24 KB
  u16* lA0 = smem;
  u16* lA1 = smem + 128 * 32;
  u16* lB0 = smem + 2 * 128 * 32;
  u16* lB1 = lB0 + 64 * 32;
  const int w = threadIdx.x >> 6, lane = threadIdx.x & 63;
  const int l15 = lane & 15, quad = lane >> 4;
  const int m0 = blockIdx.y * 128, n0 = blockIdx.x * 64;
  const int wm = w * 32;

  f32x4 acc[2][4] = {};

  const int ar = threadIdx.x >> 2, ak = (threadIdx.x & 3) * 8;
  const u16* ga = A  + (size_t)(m0 + ar) * DIM + ak;
  const u16* gb = Bt + (size_t)(n0 + ar) * DIM + ak;
  const int lo = threadIdx.x * 8;

  for (int k0 = 0; k0 < DIM; k0 += 64) {
    #pragma unroll
    for (int t = 0; t < 2; ++t) {
      gload16(ga + (size_t)t * 64 * DIM + k0,      lA0 + lo + t * 2048);
      gload16(ga + (size_t)t * 64 * DIM + k0 + 32, lA1 + lo + t * 2048);
    }
    gload16(gb + k0,      lB0 + lo);
    gload16(gb + k0 + 32, lB1 + lo);
    __syncthreads();

    #pragma unroll
    for (int kh = 0; kh < 2; ++kh) {
      const u16* lAh = kh ? lA1 : lA0;
      const u16* lBh = kh ? lB1 : lB0;
      short8 af[2], bfr[4];
      #pragma unroll
      for (int mt = 0; mt < 2; ++mt)
        af[mt] = *(const short8*)&lAh[(wm + mt * 16 + l15) * 32 + quad * 8];
      #pragma unroll
      for (int nt = 0; nt < 4; ++nt)
        bfr[nt] = *(const short8*)&lBh[(nt * 16 + l15) * 32 + quad * 8];
      #pragma unroll
      for (int mt = 0; mt < 2; ++mt)
        #pragma unroll
        for (int nt = 0; nt < 4; ++nt)
          acc[mt][nt] = __builtin_amdgcn_mfma_f32_16x16x32_bf16(af[mt], bfr[nt], acc[mt][nt], 0, 0, 0);
    }
    __syncthreads();
  }

  #pragma unroll
  for (int nt = 0; nt < 4; ++nt) {
    const int n = n0 + nt * 16 + l15;
    const float bn = bias[n];
    #pragma unroll
    for (int mt = 0; mt < 2; ++mt)
      #pragma unroll
      for (int r = 0; r < 4; ++r) {
        const int m = m0 + wm + mt * 16 + quad * 4 + r;
        outF[(size_t)m * DIM + n] = acc[mt][nt][r] + bn;   // 64B full-line segments
      }
  }
}

// ---------------- flash attention: 128-row Q tiles, S^T, max-free ----------------
// grid (8, 96). block 256 = 4 waves x 32 q-rows. K/V staged via register prefetch.
__global__ __launch_bounds__(256)
void attn_k(const u16* __restrict__ qb, const u16* __restrict__ kb,
            const u16* __restrict__ vtb, u16* __restrict__ yb) {
  const int qt = blockIdx.x, bh = blockIdx.y;
  const int w = threadIdx.x >> 6, lane = threadIdx.x & 63;
  const int l15 = lane & 15, quad = lane >> 4;

  __shared__ __align__(16) u16 lK[64 * KPAD];      // [key][d]
  __shared__ __align__(16) u16 lV[64 * KPAD];      // [d][key]
  __shared__ __align__(16) u16 lP[4][32 * KPAD];   // per-wave [qrow 0..31][key]

  const u16* qb0 = qb + ((size_t)bh * SEQ + qt * 128 + w * 32 + l15) * HD;
  short8 aq[2][2];
  #pragma unroll
  for (int qg = 0; qg < 2; ++qg) {
    aq[qg][0] = *(const short8*)(qb0 + (size_t)qg * 16 * HD + quad * 8);
    aq[qg][1] = *(const short8*)(qb0 + (size_t)qg * 16 * HD + 32 + quad * 8);
  }

  f32x4 o[2][4] = {};
  float rs[2] = {0.f, 0.f};

  const u16* kcbase = kb + (size_t)bh * SEQ * HD;
  const u16* vbase  = vtb + (size_t)bh * HD * SEQ;
  u16* lPw = &lP[w][0];

  const int cid0 = threadIdx.x, cid1 = threadIdx.x + 256;
  const int sofs0 = (cid0 >> 3) * KPAD + (cid0 & 7) * 8;
  const int sofs1 = (cid1 >> 3) * KPAD + (cid1 & 7) * 8;
  const u16* vg0 = vbase + (size_t)(cid0 >> 3) * SEQ + (cid0 & 7) * 8;
  const u16* vg1 = vbase + (size_t)(cid1 >> 3) * SEQ + (cid1 & 7) * 8;

  short8 pk0 = *(const short8*)(kcbase + cid0 * 8);
  short8 pk1 = *(const short8*)(kcbase + cid1 * 8);
  short8 pv0 = *(const short8*)vg0;
  short8 pv1 = *(const short8*)vg1;

  for (int kc = 0; kc < 16; ++kc) {
    *(short8*)&lK[sofs0] = pk0;
    *(short8*)&lK[sofs1] = pk1;
    *(short8*)&lV[sofs0] = pv0;
    *(short8*)&lV[sofs1] = pv1;
    __syncthreads();

    const int kn = (kc < 15) ? kc + 1 : 15;
    pk0 = *(const short8*)(kcbase + kn * 64 * HD + cid0 * 8);
    pk1 = *(const short8*)(kcbase + kn * 64 * HD + cid1 * 8);
    pv0 = *(const short8*)(vg0 + kn * 64);
    pv1 = *(const short8*)(vg1 + kn * 64);

    short8 ak0[4], ak1[4], bv0[4], bv1[4];
    #pragma unroll
    for (int nt = 0; nt < 4; ++nt) {
      ak0[nt] = *(const short8*)&lK[(nt * 16 + l15) * KPAD + quad * 8];
      ak1[nt] = *(const short8*)&lK[(nt * 16 + l15) * KPAD + 32 + quad * 8];
      bv0[nt] = *(const short8*)&lV[(nt * 16 + l15) * KPAD + quad * 8];
      bv1[nt] = *(const short8*)&lV[(nt * 16 + l15) * KPAD + 32 + quad * 8];
    }

    #pragma unroll
    for (int qg = 0; qg < 2; ++qg) {
      f32x4 st[4] = {};
      #pragma unroll
      for (int nt = 0; nt < 4; ++nt) {
        st[nt] = __builtin_amdgcn_mfma_f32_16x16x32_bf16(ak0[nt], aq[qg][0], st[nt], 0, 0, 0);
        st[nt] = __builtin_amdgcn_mfma_f32_16x16x32_bf16(ak1[nt], aq[qg][1], st[nt], 0, 0, 0);
      }

      #pragma unroll
      for (int nt = 0; nt < 4; ++nt) {
        float p0 = __builtin_amdgcn_exp2f(st[nt][0]);
        float p1 = __builtin_amdgcn_exp2f(st[nt][1]);
        float p2 = __builtin_amdgcn_exp2f(st[nt][2]);
        float p3 = __builtin_amdgcn_exp2f(st[nt][3]);
        float t0 = __uint_as_float(__float_as_uint(p0) & 0xffff0000u);
        float t1 = __uint_as_float(__float_as_uint(p1) & 0xffff0000u);
        float t2 = __uint_as_float(__float_as_uint(p2) & 0xffff0000u);
        float t3 = __uint_as_float(__float_as_uint(p3) & 0xffff0000u);
        rs[qg] += (t0 + t1) + (t2 + t3);
        int2v pk;
        pk.x = (int)__builtin_amdgcn_perm(__float_as_uint(p1), __float_as_uint(p0), 0x07060302u);
        pk.y = (int)__builtin_amdgcn_perm(__float_as_uint(p3), __float_as_uint(p2), 0x07060302u);
        *(int2v*)&lPw[(qg * 16 + l15) * KPAD + nt * 16 + quad * 4] = pk;
      }
      const short8 ap0 = *(const short8*)&lPw[(qg * 16 + l15) * KPAD + quad * 8];
      const short8 ap1 = *(const short8*)&lPw[(qg * 16 + l15) * KPAD + 32 + quad * 8];
      #pragma unroll
      for (int nt = 0; nt < 4; ++nt) {
        o[qg][nt] = __builtin_amdgcn_mfma_f32_16x16x32_bf16(ap0, bv0[nt], o[qg][nt], 0, 0, 0);
        o[qg][nt] = __builtin_amdgcn_mfma_f32_16x16x32_bf16(ap1, bv1[nt], o[qg][nt], 0, 0, 0);
      }
    }
    __syncthreads();
  }

  const int b = bh / HEADS, h = bh % HEADS;
  #pragma unroll
  for (int qg = 0; qg < 2; ++qg) {
    rs[qg] += __shfl_xor(rs[qg], 16);
    rs[qg] += __shfl_xor(rs[qg], 32);
    #pragma unroll
    for (int r = 0; r < 4; ++r) {
      const float inv = 1.0f / __shfl(rs[qg], quad * 4 + r, 16);
      #pragma unroll
      for (int nt = 0; nt < 4; ++nt)
        lPw[(qg * 16 + quad * 4 + r) * KPAD + nt * 16 + l15] = f2bf(o[qg][nt][r] * inv);
    }
  }

  u16* dst = yb + ((size_t)b * SEQ + qt * 128 + w * 32) * DIM + h * HD;
  const int erow = lane >> 3, ec8 = (lane & 7) * 8;
  #pragma unroll
  for (int j = 0; j < 4; ++j) {
    const int trow = j * 8 + erow;
    short8 vrow = *(const short8*)&lPw[trow * KPAD + ec8];
    *(short8*)(dst + (size_t)trow * DIM + ec8) = vrow;
  }
}

// ---------------- launcher ----------------
extern "C" void kernel_launch(void* const* d_in, const int* in_sizes, int n_in,
                              void* d_out, int out_size, void* d_ws, size_t ws_size,
                              hipStream_t stream) {
  const float* x     = (const float*)d_in[0];
  const float* Wqkv  = (const float*)d_in[1];
  const float* bqkv  = (const float*)d_in[2];
  const float* Wproj = (const float*)d_in[3];
  const float* bproj = (const float*)d_in[4];
  float* out = (float*)d_out;

  u16* xb     = (u16*)d_ws;                       // 8192*768
  u16* wqkvt  = xb + (size_t)MTOK * DIM;
  u16* wprojt = wqkvt + (size_t)NQKV * DIM;
  u16* qkv_b  = wprojt + (size_t)DIM * DIM;       // q,k: [t][d]; v-slot holds vt [d][t]
  u16* y_b    = qkv_b + 3 * PSZ;

  cvt_all_k<<<XBLK + QTBLK + (DIM / 32) * (DIM / 32), 256, 0, stream>>>(
      x, Wqkv, Wproj, xb, wqkvt, wprojt);

  gemm_qkv<<<dim3(NQKV / 128, MTOK / 128), 256, 0, stream>>>(xb, wqkvt, bqkv, qkv_b);

  attn_k<<<dim3(SEQ / 128, BATCH * HEADS), 256, 0, stream>>>(
      qkv_b, qkv_b + PSZ, qkv_b + 2 * PSZ, y_b);

  gemm_proj<<<dim3(DIM / 64, MTOK / 128), 256, 0, stream>>>(y_b, wprojt, bproj, out);
}

// Round 10
// 195.502 us; speedup vs baseline: 1.0552x; 1.0417x over previous
//
#include <hip/hip_runtime.h>

typedef unsigned short u16;
typedef __attribute__((ext_vector_type(8))) short short8;
typedef __attribute__((ext_vector_type(4))) short short4v;
typedef __attribute__((ext_vector_type(2))) int int2v;
typedef __attribute__((ext_vector_type(4))) float f32x4;

#define DIM   768
#define HEADS 12
#define HD    64
#define BATCH 8
#define SEQ   1024
#define MTOK  (BATCH*SEQ)   /* 8192 */
#define NQKV  (3*DIM)       /* 2304 */
#define KPAD  72            /* attn LDS row stride: 36 dwords breaks 32-bank alias */
#define EPAD  66            /* gemm epilogue stage stride */
#define PSZ   ((size_t)BATCH*HEADS*SEQ*HD)   /* one of q/k/v */
#define SCQ   0.1803368801f /* hd^-0.5 * log2(e), folded into stored q */

__device__ __forceinline__ u16 f2bf(float f) {
  unsigned x = __float_as_uint(f);
  x += 0x7fffu + ((x >> 16) & 1u);      // RNE
  return (u16)(x >> 16);
}

__device__ __forceinline__ void gload16(const u16* g, u16* l) {
  __builtin_amdgcn_global_load_lds(
      (const __attribute__((address_space(1))) unsigned int*)g,
      (__attribute__((address_space(3))) unsigned int*)l, 16, 0, 0);
}

// ---------------- fused conversions: x->bf16, Wqkv^T, Wproj^T ----------------
#define XBLK 6144            /* MTOK*DIM/4/256 */
#define QTBLK 1728           /* (NQKV/32)*(DIM/32) */
__global__ void cvt_all_k(const float* __restrict__ x,
                          const float* __restrict__ Wqkv,
                          const float* __restrict__ Wproj,
                          u16* __restrict__ xb, u16* __restrict__ wqkvt,
                          u16* __restrict__ wprojt) {
  __shared__ u16 tile[32][33];
  const int blk = blockIdx.x;
  if (blk < XBLK) {
    const int i = blk * 256 + threadIdx.x;
    float4 f = ((const float4*)x)[i];
    short4v o;
    o.x = (short)f2bf(f.x); o.y = (short)f2bf(f.y);
    o.z = (short)f2bf(f.z); o.w = (short)f2bf(f.w);
    ((short4v*)xb)[i] = o;
    return;
  }
  const float* in; u16* out; int K, N, n0, k0;
  if (blk < XBLK + QTBLK) {
    const int t = blk - XBLK;
    in = Wqkv; out = wqkvt; K = DIM; N = NQKV;
    n0 = (t % (NQKV / 32)) * 32; k0 = (t / (NQKV / 32)) * 32;
  } else {
    const int t = blk - XBLK - QTBLK;
    in = Wproj; out = wprojt; K = DIM; N = DIM;
    n0 = (t % (DIM / 32)) * 32; k0 = (t / (DIM / 32)) * 32;
  }
  const int tx = threadIdx.x & 31, ty = threadIdx.x >> 5;
  #pragma unroll
  for (int i = 0; i < 32; i += 8)
    tile[ty + i][tx] = f2bf(in[(size_t)(k0 + ty + i) * N + n0 + tx]);
  __syncthreads();
  #pragma unroll
  for (int i = 0; i < 32; i += 8)
    out[(size_t)(n0 + ty + i) * K + k0 + tx] = tile[tx][ty + i];
}

// ---------------- GEMM1: qkv = x * Wqkv^T + b, 128x128 tile, BK=64 ----------------
// 1D grid 1152, XCD-swizzled: xcd=b&7 pins each m-row-group to one XCD so its
// x-slice stays L2-resident while n sweeps. q/k: LDS-transpose epilogue;
// v: direct short4 stores as vt [bh][d][t].
__global__ __launch_bounds__(256)
void gemm_qkv(const u16* __restrict__ A, const u16* __restrict__ Bt,
              const float* __restrict__ bias, u16* __restrict__ qkv) {
  __shared__ __align__(16) u16 smem[4 * 128 * 32];   // 32 KB
  u16* lA0 = smem;
  u16* lA1 = smem + 128 * 32;
  u16* lB0 = smem + 2 * 128 * 32;
  u16* lB1 = smem + 3 * 128 * 32;
  const int w = threadIdx.x >> 6, lane = threadIdx.x & 63;
  const int l15 = lane & 15, quad = lane >> 4;
  // XCD swizzle: b%8 = XCD. j/8 -> n-block (slow), (j&7)*8+xcd -> m-block.
  const int b_ = blockIdx.x;
  const int xcd = b_ & 7, j = b_ >> 3;
  const int m0 = ((j & 7) * 8 + xcd) * 128;   // 0..63 * 128
  const int n0 = (j >> 3) * 128;              // 0..17 * 128
  const int wm = (w >> 1) * 64, wn = (w & 1) * 64;

  f32x4 acc[4][4] = {};

  const int ar = threadIdx.x >> 2, ak = (threadIdx.x & 3) * 8;
  const u16* ga = A  + (size_t)(m0 + ar) * DIM + ak;
  const u16* gb = Bt + (size_t)(n0 + ar) * DIM + ak;
  const int lo = threadIdx.x * 8;

  for (int k0 = 0; k0 < DIM; k0 += 64) {
    #pragma unroll
    for (int t = 0; t < 2; ++t) {
      gload16(ga + (size_t)t * 64 * DIM + k0,      lA0 + lo + t * 2048);
      gload16(ga + (size_t)t * 64 * DIM + k0 + 32, lA1 + lo + t * 2048);
      gload16(gb + (size_t)t * 64 * DIM + k0,      lB0 + lo + t * 2048);
      gload16(gb + (size_t)t * 64 * DIM + k0 + 32, lB1 + lo + t * 2048);
    }
    __syncthreads();

    #pragma unroll
    for (int kh = 0; kh < 2; ++kh) {
      const u16* lAh = kh ? lA1 : lA0;
      const u16* lBh = kh ? lB1 : lB0;
      short8 af[4], bfr[4];
      #pragma unroll
      for (int mt = 0; mt < 4; ++mt)
        af[mt] = *(const short8*)&lAh[(wm + mt * 16 + l15) * 32 + quad * 8];
      #pragma unroll
      for (int nt = 0; nt < 4; ++nt)
        bfr[nt] = *(const short8*)&lBh[(wn + nt * 16 + l15) * 32 + quad * 8];
      #pragma unroll
      for (int mt = 0; mt < 4; ++mt)
        #pragma unroll
        for (int nt = 0; nt < 4; ++nt)
          acc[mt][nt] = __builtin_amdgcn_mfma_f32_16x16x32_bf16(af[mt], bfr[nt], acc[mt][nt], 0, 0, 0);
    }
    __syncthreads();
  }

  const int bb = m0 >> 10;
  const int tb0 = (m0 & 1023) + wm;
  const int nh = n0 + wn;
  const int part = nh / DIM, idx = nh - part * DIM;
  const int h = idx >> 6;

  float bnl[4];
  #pragma unroll
  for (int nt = 0; nt < 4; ++nt) bnl[nt] = bias[nh + nt * 16 + l15];

  if (part < 2) {
    u16* dstbase = qkv + part * PSZ + ((size_t)(bb * HEADS + h) * SEQ + tb0) * HD;
    const float qsc = (part == 0) ? SCQ : 1.0f;
    const int erow = lane >> 3, ec8 = (lane & 7) * 8;
    #pragma unroll
    for (int mt = 0; mt < 4; ++mt) {
      u16* ep = smem + w * (16 * EPAD) + (mt & 1) * (4 * 16 * EPAD);
      #pragma unroll
      for (int nt = 0; nt < 4; ++nt)
        #pragma unroll
        for (int r = 0; r < 4; ++r)
          ep[(quad * 4 + r) * EPAD + nt * 16 + l15] = f2bf((acc[mt][nt][r] + bnl[nt]) * qsc);
      #pragma unroll
      for (int j2 = 0; j2 < 2; ++j2) {
        const int trow = j2 * 8 + erow;
        short8 vrow = *(const short8*)&ep[trow * EPAD + ec8];
        *(short8*)(dstbase + (size_t)(mt * 16 + trow) * HD + ec8) = vrow;
      }
    }
  } else {
    u16* vrow0 = qkv + 2 * PSZ + (size_t)(bb * HEADS + h) * HD * SEQ;
    #pragma unroll
    for (int nt = 0; nt < 4; ++nt) {
      const int d = nt * 16 + l15;
      u16* trow = vrow0 + (size_t)d * SEQ + tb0 + quad * 4;
      #pragma unroll
      for (int mt = 0; mt < 4; ++mt) {
        short4v pv;
        pv.x = (short)f2bf(acc[mt][nt][0] + bnl[nt]);
        pv.y = (short)f2bf(acc[mt][nt][1] + bnl[nt]);
        pv.z = (short)f2bf(acc[mt][nt][2] + bnl[nt]);
        pv.w = (short)f2bf(acc[mt][nt][3] + bnl[nt]);
        *(short4v*)(trow + mt * 16) = pv;
      }
    }
  }
}

// ---------------- GEMM2: out = y * Wproj^T + b (fp32 out, 128x64, BK=64) ----------------
// 1D grid 768, XCD-swizzled like gemm_qkv.
__global__ __launch_bounds__(256)
void gemm_proj(const u16* __restrict__ A, const u16* __restrict__ Bt,
               const float* __restrict__ bias, float* __restrict__ outF) {
  __shared__ __align__(16) u16 smem[2 * 128 * 32 + 2 * 64 * 32];   // 24 KB
  u16* lA0 = smem;
  u16* lA1 = smem + 128 * 32;
  u16* lB0 = smem + 2 * 128 * 32;
  u16* lB1 = lB0 + 64 * 32;
  const int w = threadIdx.x >> 6, lane = threadIdx.x & 63;
  const int l15 = lane & 15, quad = lane >> 4;
  const int b_ = blockIdx.x;
  const int xcd = b_ & 7, j = b_ >> 3;
  const int m0 = ((j & 7) * 8 + xcd) * 128;   // 0..63 * 128
  const int n0 = (j >> 3) * 64;               // 0..11 * 64
  const int wm = w * 32;

  f32x4 acc[2][4] = {};

  const int ar = threadIdx.x >> 2, ak = (threadIdx.x & 3) * 8;
  const u16* ga = A  + (size_t)(m0 + ar) * DIM + ak;
  const u16* gb = Bt + (size_t)(n0 + ar) * DIM + ak;
  const int lo = threadIdx.x * 8;

  for (int k0 = 0; k0 < DIM; k0 += 64) {
    #pragma unroll
    for (int t = 0; t < 2; ++t) {
      gload16(ga + (size_t)t * 64 * DIM + k0,      lA0 + lo + t * 2048);
      gload16(ga + (size_t)t * 64 * DIM + k0 + 32, lA1 + lo + t * 2048);
    }
    gload16(gb + k0,      lB0 + lo);
    gload16(gb + k0 + 32, lB1 + lo);
    __syncthreads();

    #pragma unroll
    for (int kh = 0; kh < 2; ++kh) {
      const u16* lAh = kh ? lA1 : lA0;
      const u16* lBh = kh ? lB1 : lB0;
      short8 af[2], bfr[4];
      #pragma unroll
      for (int mt = 0; mt < 2; ++mt)
        af[mt] = *(const short8*)&lAh[(wm + mt * 16 + l15) * 32 + quad * 8];
      #pragma unroll
      for (int nt = 0; nt < 4; ++nt)
        bfr[nt] = *(const short8*)&lBh[(nt * 16 + l15) * 32 + quad * 8];
      #pragma unroll
      for (int mt = 0; mt < 2; ++mt)
        #pragma unroll
        for (int nt = 0; nt < 4; ++nt)
          acc[mt][nt] = __builtin_amdgcn_mfma_f32_16x16x32_bf16(af[mt], bfr[nt], acc[mt][nt], 0, 0, 0);
    }
    __syncthreads();
  }

  #pragma unroll
  for (int nt = 0; nt < 4; ++nt) {
    const int n = n0 + nt * 16 + l15;
    const float bn = bias[n];
    #pragma unroll
    for (int mt = 0; mt < 2; ++mt)
      #pragma unroll
      for (int r = 0; r < 4; ++r) {
        const int m = m0 + wm + mt * 16 + quad * 4 + r;
        outF[(size_t)m * DIM + n] = acc[mt][nt][r] + bn;
      }
  }
}

// ---------------- flash attention: 128-row Q tiles, S^T, max-free ----------------
// grid (96, 8): bh = blockIdx.x so all 8 q-tiles of a bh land on ONE XCD
// (b%8 = bh%8 since gridDim.x=96 is a multiple of 8) -> K/V L2-resident.
__global__ __launch_bounds__(256)
void attn_k(const u16* __restrict__ qb, const u16* __restrict__ kb,
            const u16* __restrict__ vtb, u16* __restrict__ yb) {
  const int bh = blockIdx.x, qt = blockIdx.y;
  const int w = threadIdx.x >> 6, lane = threadIdx.x & 63;
  const int l15 = lane & 15, quad = lane >> 4;

  __shared__ __align__(16) u16 lK[64 * KPAD];      // [key][d]
  __shared__ __align__(16) u16 lV[64 * KPAD];      // [d][key]
  __shared__ __align__(16) u16 lP[4][32 * KPAD];   // per-wave [qrow 0..31][key]

  const u16* qb0 = qb + ((size_t)bh * SEQ + qt * 128 + w * 32 + l15) * HD;
  short8 aq[2][2];
  #pragma unroll
  for (int qg = 0; qg < 2; ++qg) {
    aq[qg][0] = *(const short8*)(qb0 + (size_t)qg * 16 * HD + quad * 8);
    aq[qg][1] = *(const short8*)(qb0 + (size_t)qg * 16 * HD + 32 + quad * 8);
  }

  f32x4 o[2][4] = {};
  float rs[2] = {0.f, 0.f};

  const u16* kcbase = kb + (size_t)bh * SEQ * HD;
  const u16* vbase  = vtb + (size_t)bh * HD * SEQ;
  u16* lPw = &lP[w][0];

  const int cid0 = threadIdx.x, cid1 = threadIdx.x + 256;
  const int sofs0 = (cid0 >> 3) * KPAD + (cid0 & 7) * 8;
  const int sofs1 = (cid1 >> 3) * KPAD + (cid1 & 7) * 8;
  const u16* vg0 = vbase + (size_t)(cid0 >> 3) * SEQ + (cid0 & 7) * 8;
  const u16* vg1 = vbase + (size_t)(cid1 >> 3) * SEQ + (cid1 & 7) * 8;

  short8 pk0 = *(const short8*)(kcbase + cid0 * 8);
  short8 pk1 = *(const short8*)(kcbase + cid1 * 8);
  short8 pv0 = *(const short8*)vg0;
  short8 pv1 = *(const short8*)vg1;

  for (int kc = 0; kc < 16; ++kc) {
    *(short8*)&lK[sofs0] = pk0;
    *(short8*)&lK[sofs1] = pk1;
    *(short8*)&lV[sofs0] = pv0;
    *(short8*)&lV[sofs1] = pv1;
    __syncthreads();

    const int kn = (kc < 15) ? kc + 1 : 15;
    pk0 = *(const short8*)(kcbase + kn * 64 * HD + cid0 * 8);
    pk1 = *(const short8*)(kcbase + kn * 64 * HD + cid1 * 8);
    pv0 = *(const short8*)(vg0 + kn * 64);
    pv1 = *(const short8*)(vg1 + kn * 64);

    short8 ak0[4], ak1[4], bv0[4], bv1[4];
    #pragma unroll
    for (int nt = 0; nt < 4; ++nt) {
      ak0[nt] = *(const short8*)&lK[(nt * 16 + l15) * KPAD + quad * 8];
      ak1[nt] = *(const short8*)&lK[(nt * 16 + l15) * KPAD + 32 + quad * 8];
      bv0[nt] = *(const short8*)&lV[(nt * 16 + l15) * KPAD + quad * 8];
      bv1[nt] = *(const short8*)&lV[(nt * 16 + l15) * KPAD + 32 + quad * 8];
    }

    #pragma unroll
    for (int qg = 0; qg < 2; ++qg) {
      f32x4 st[4] = {};
      #pragma unroll
      for (int nt = 0; nt < 4; ++nt) {
        st[nt] = __builtin_amdgcn_mfma_f32_16x16x32_bf16(ak0[nt], aq[qg][0], st[nt], 0, 0, 0);
        st[nt] = __builtin_amdgcn_mfma_f32_16x16x32_bf16(ak1[nt], aq[qg][1], st[nt], 0, 0, 0);
      }

      #pragma unroll
      for (int nt = 0; nt < 4; ++nt) {
        float p0 = __builtin_amdgcn_exp2f(st[nt][0]);
        float p1 = __builtin_amdgcn_exp2f(st[nt][1]);
        float p2 = __builtin_amdgcn_exp2f(st[nt][2]);
        float p3 = __builtin_amdgcn_exp2f(st[nt][3]);
        float t0 = __uint_as_float(__float_as_uint(p0) & 0xffff0000u);
        float t1 = __uint_as_float(__float_as_uint(p1) & 0xffff0000u);
        float t2 = __uint_as_float(__float_as_uint(p2) & 0xffff0000u);
        float t3 = __uint_as_float(__float_as_uint(p3) & 0xffff0000u);
        rs[qg] += (t0 + t1) + (t2 + t3);
        int2v pk;
        pk.x = (int)__builtin_amdgcn_perm(__float_as_uint(p1), __float_as_uint(p0), 0x07060302u);
        pk.y = (int)__builtin_amdgcn_perm(__float_as_uint(p3), __float_as_uint(p2), 0x07060302u);
        *(int2v*)&lPw[(qg * 16 + l15) * KPAD + nt * 16 + quad * 4] = pk;
      }
      const short8 ap0 = *(const short8*)&lPw[(qg * 16 + l15) * KPAD + quad * 8];
      const short8 ap1 = *(const short8*)&lPw[(qg * 16 + l15) * KPAD + 32 + quad * 8];
      #pragma unroll
      for (int nt = 0; nt < 4; ++nt) {
        o[qg][nt] = __builtin_amdgcn_mfma_f32_16x16x32_bf16(ap0, bv0[nt], o[qg][nt], 0, 0, 0);
        o[qg][nt] = __builtin_amdgcn_mfma_f32_16x16x32_bf16(ap1, bv1[nt], o[qg][nt], 0, 0, 0);
      }
    }
    __syncthreads();
  }

  const int b = bh / HEADS, h = bh % HEADS;
  #pragma unroll
  for (int qg = 0; qg < 2; ++qg) {
    rs[qg] += __shfl_xor(rs[qg], 16);
    rs[qg] += __shfl_xor(rs[qg], 32);
    #pragma unroll
    for (int r = 0; r < 4; ++r) {
      const float inv = 1.0f / __shfl(rs[qg], quad * 4 + r, 16);
      #pragma unroll
      for (int nt = 0; nt < 4; ++nt)
        lPw[(qg * 16 + quad * 4 + r) * KPAD + nt * 16 + l15] = f2bf(o[qg][nt][r] * inv);
    }
  }

  u16* dst = yb + ((size_t)b * SEQ + qt * 128 + w * 32) * DIM + h * HD;
  const int erow = lane >> 3, ec8 = (lane & 7) * 8;
  #pragma unroll
  for (int j = 0; j < 4; ++j) {
    const int trow = j * 8 + erow;
    short8 vrow = *(const short8*)&lPw[trow * KPAD + ec8];
    *(short8*)(dst + (size_t)trow * DIM + ec8) = vrow;
  }
}

// ---------------- launcher ----------------
extern "C" void kernel_launch(void* const* d_in, const int* in_sizes, int n_in,
                              void* d_out, int out_size, void* d_ws, size_t ws_size,
                              hipStream_t stream) {
  const float* x     = (const float*)d_in[0];
  const float* Wqkv  = (const float*)d_in[1];
  const float* bqkv  = (const float*)d_in[2];
  const float* Wproj = (const float*)d_in[3];
  const float* bproj = (const float*)d_in[4];
  float* out = (float*)d_out;

  u16* xb     = (u16*)d_ws;                       // 8192*768
  u16* wqkvt  = xb + (size_t)MTOK * DIM;
  u16* wprojt = wqkvt + (size_t)NQKV * DIM;
  u16* qkv_b  = wprojt + (size_t)DIM * DIM;       // q,k: [t][d]; v-slot holds vt [d][t]
  u16* y_b    = qkv_b + 3 * PSZ;

  cvt_all_k<<<XBLK + QTBLK + (DIM / 32) * (DIM / 32), 256, 0, stream>>>(
      x, Wqkv, Wproj, xb, wqkvt, wprojt);

  gemm_qkv<<<1152, 256, 0, stream>>>(xb, wqkvt, bqkv, qkv_b);

  attn_k<<<dim3(BATCH * HEADS, SEQ / 128), 256, 0, stream>>>(
      qkv_b, qkv_b + PSZ, qkv_b + 2 * PSZ, y_b);

  gemm_proj<<<768, 256, 0, stream>>>(y_b, wprojt, bproj, out);
}